// Round 6
// baseline (1441.873 us; speedup 1.0000x reference)
//
#include <hip/hip_runtime.h>
#include <hip/hip_bf16.h>

// Problem constants
#define BATCH 512
#define TT 60
#define EDIM 300
#define HDIM 512
#define KP1 2112         // padded K for head GEMM (2053 -> 2112)
#define MDIM 256
#define V48 2400000      // 50000 tokens * 48 runs
#define WCG 229376       // wf elems per cg slice: 14 chunks * 16384

typedef __bf16 bf16x4 __attribute__((ext_vector_type(4)));
typedef __bf16 bf16x8 __attribute__((ext_vector_type(8)));
typedef float  f32x16 __attribute__((ext_vector_type(16)));

#define GLL16(g, l) __builtin_amdgcn_global_load_lds( \
    (const __attribute__((address_space(1))) void*)(g), \
    (__attribute__((address_space(3))) void*)(l), 16, 0, 0)

#define SBAR()  __builtin_amdgcn_s_barrier()
#define SCHED0() __builtin_amdgcn_sched_barrier(0)

__device__ __forceinline__ float sigm(float x) {
    return 1.0f / (1.0f + __expf(-x));
}
__device__ __forceinline__ float tanh_fast(float x) {
    float e = __expf(-2.0f * fabsf(x));
    float r = (1.0f - e) / (1.0f + e);
    return x >= 0.0f ? r : -r;
}

// ---------------------------------------------------------------------------
// NEW decomposition (deep-pipeline): 256 blocks x 512 thr = 16 tiles x 16 cg,
// 1 block/CU, 8 waves = (s:2 row-half) x (kg:2 k-half) x (n:2 gate-pair).
// Block owns 64 rows x 128 gate-cols (= 4 gates x 32 h-cols, h-cols
// [cg*32, cg*32+32)). K split into 14 chunks of 64.
//
// Wf (weights) NEW layout: [cg:16][cc:14][slot:32][lane:64][e:8] where
//   slot = (jp*4 + gate)*2 + plane, jp = (k>>4)&3 within the chunk,
//   lane = (k-half8)*32 + hcol-in-cg, e = k&7. One slot = one 32x32x16
//   B fragment (32 cols x 16 k). Chunk = 32 KB.
// A-side layouts (embB, XfH) UNCHANGED from round 5; only per-wave read
// addressing changes (wave kg reads jj in {2kg, 2kg+1} of each 64-k block).
//
// QUAD-buffered pipeline: during chunk cc issue stage(cc+3) (4 GLL16/wave)
// then A(cc+2) (4 loads/wave). Stage slack = 3 chunks, A slack = 2 chunks.
// FIFO property: the compiler's register wait on A(cc) (issued after
// stage(cc+1)) retires stage(cc+1) and older -> manual vmcnt gates
// {cc0:16, cc2:24, else:20} are exact-or-vacuous insurance. Never vmcnt(0)
// in the loop. Raw s_barrier per chunk protects buffer rotation.
// Boundary: [tok(t+1); publish(2 sc1); stage(0,1,2); A(0),A(1); vmcnt(20)
// (retires tok+publish only); SBAR; signal]. h-poll at cc==4, before A(6)
// (first XfH read) is issued.
// Per-step sync: per-tile LLC counter (16 blocks), ALL RELAXED. c/h state in
// registers. cg-pair per XCD keeps the 918 KB weight slice L2-resident;
// every XCD hosts all 16 tiles (2 blocks each) -> automatic load balance,
// and the 60-step critical tile owns its 16 CUs exclusively.
// ---------------------------------------------------------------------------

__global__ __launch_bounds__(256) void sort_rows(const int* __restrict__ sl1,
                                                 const int* __restrict__ sl2,
                                                 int* __restrict__ rowinfo,
                                                 unsigned* __restrict__ step_done) {
    __shared__ unsigned cnt[61];
    __shared__ unsigned off[61];
    int tid = threadIdx.x;
    if (tid < 61) cnt[tid] = 0;
    if (tid >= 64 && tid < 80) step_done[tid - 64] = 0;
    __syncthreads();
    for (int i = tid; i < 1024; i += 256) {
        int sl = (i < 512) ? sl1[i] : sl2[i - 512];
        atomicAdd(&cnt[60 - sl], 1u);
    }
    __syncthreads();
    if (tid == 0) {
        unsigned s = 0;
        for (int k = 0; k < 61; ++k) { off[k] = s; s += cnt[k]; }
    }
    __syncthreads();
    for (int i = tid; i < 1024; i += 256) {
        int sc = i >= 512;
        int b = i & 511;
        int sl = sc ? sl2[b] : sl1[b];
        unsigned pos = atomicAdd(&off[60 - sl], 1u);
        rowinfo[pos] = b | (sc << 15) | (sl << 20);
    }
}

// prep_w: lstm_kernel [812][2048] fp32 -> Wf NEW layout (hi/lo, k-remapped:
//   new k<300 -> kern k; 300..383 -> 0; >=384 -> kern k-84)
__global__ __launch_bounds__(256) void prep_w(const float* __restrict__ kern,
                                              __bf16* __restrict__ wf) {
    __shared__ float tile[64][65];
    int bk = blockIdx.x % 14;
    int bn = blockIdx.x / 14;
    int k0 = bk * 64, n0 = bn * 64;
    int tid = threadIdx.x;
#pragma unroll
    for (int i = 0; i < 16; ++i) {
        int id = i * 256 + tid;
        int kk = id >> 6, nn = id & 63;
        int kg = k0 + kk;
        int src = (kg < 300) ? kg : (kg >= 384 ? kg - 84 : -1);
        tile[kk][nn] = (src >= 0) ? kern[(size_t)src * 2048 + n0 + nn] : 0.0f;
    }
    __syncthreads();
    int gate = n0 >> 9;
#pragma unroll
    for (int i = 0; i < 2; ++i) {
        int id = i * 256 + tid;          // 0..511 = nn(64) x k8(8)
        int nn = id >> 3, k8 = id & 7;
        bf16x8 hv, lv;
#pragma unroll
        for (int j = 0; j < 8; ++j) {
            float v = tile[k8 * 8 + j][nn];
            __bf16 h = (__bf16)v;
            hv[j] = h;
            lv[j] = (__bf16)(v - (float)h);
        }
        int cg = ((n0 & 511) >> 5) + (nn >> 5);
        int hc = nn & 31;
        int kglob = k0 + k8 * 8;
        int cc = kglob >> 6;
        int jp = (kglob >> 4) & 3;
        int half = (kglob >> 3) & 1;
        int slot = (jp * 4 + gate) * 2;
        size_t o = ((size_t)(cg * 14 + cc) * 32 + slot) * 512 + (half * 32 + hc) * 8;
        *(bf16x8*)(wf + o) = hv;
        *(bf16x8*)(wf + o + 512) = lv;
    }
}

__global__ __launch_bounds__(256) void prep_w1(const float* __restrict__ W1,
                                               __bf16* __restrict__ w1h,
                                               __bf16* __restrict__ w1l) {
    __shared__ float tile[64][65];
    int bk = blockIdx.x % 33;
    int bn = blockIdx.x / 33;
    int k0 = bk * 64, n0 = bn * 64;
    int tid = threadIdx.x;
#pragma unroll
    for (int i = 0; i < 16; ++i) {
        int id = i * 256 + tid;
        int kk = id >> 6, nn = id & 63;
        int kg = k0 + kk;
        tile[kk][nn] = (kg < 2053) ? W1[(size_t)kg * MDIM + n0 + nn] : 0.0f;
    }
    __syncthreads();
#pragma unroll
    for (int i = 0; i < 2; ++i) {
        int id = i * 256 + tid;
        int nn = id >> 3, k8 = (id & 7) * 8;
        bf16x8 hv, lv;
#pragma unroll
        for (int j = 0; j < 8; ++j) {
            float v = tile[k8 + j][nn];
            __bf16 h = (__bf16)v;
            hv[j] = h;
            lv[j] = (__bf16)(v - (float)h);
        }
        size_t o = (size_t)(n0 + nn) * KP1 + k0 + k8;
        *(bf16x8*)(w1h + o) = hv;
        *(bf16x8*)(w1l + o) = lv;
    }
}

// prep_emb: embeddings [50000][300] fp32 -> embB [50000][hi:384 | lo:384] bf16
__global__ __launch_bounds__(256) void prep_emb(const float* __restrict__ emb,
                                                __bf16* __restrict__ embB) {
    int id = blockIdx.x * 256 + threadIdx.x;
    if (id >= V48) return;
    int tok = id / 48;
    int k8 = id - tok * 48;
    int k0 = k8 * 8;
    float vv[8];
    const float* er = emb + (size_t)tok * EDIM + k0;
    if (k0 + 8 <= EDIM) {
        float4 f0 = *(const float4*)er;
        float4 f1 = *(const float4*)(er + 4);
        vv[0] = f0.x; vv[1] = f0.y; vv[2] = f0.z; vv[3] = f0.w;
        vv[4] = f1.x; vv[5] = f1.y; vv[6] = f1.z; vv[7] = f1.w;
    } else if (k0 < EDIM) {          // k0 == 296: 4 real + 4 pad
        float4 f0 = *(const float4*)er;
        vv[0] = f0.x; vv[1] = f0.y; vv[2] = f0.z; vv[3] = f0.w;
        vv[4] = vv[5] = vv[6] = vv[7] = 0.f;
    } else {
#pragma unroll
        for (int j = 0; j < 8; ++j) vv[j] = 0.f;
    }
    bf16x8 hv, lv;
#pragma unroll
    for (int j = 0; j < 8; ++j) {
        __bf16 h = (__bf16)vv[j];
        hv[j] = h;
        lv[j] = (__bf16)(vv[j] - (float)h);
    }
    size_t o = (size_t)tok * 768 + k0;
    *(bf16x8*)(embB + o) = hv;
    *(bf16x8*)(embB + o + 384) = lv;
}

// ---------------------------------------------------------------------------
// Persistent fused LSTM, deep pipeline. 256 blocks x 512 thr, 1 block/CU.
// ---------------------------------------------------------------------------
#define ZST 136

__global__ __launch_bounds__(512, 1) void lstm_all(
    const int* __restrict__ in1, const int* __restrict__ in2,
    const int* __restrict__ rowinfo,
    const __bf16* __restrict__ embB, const float* __restrict__ bias,
    const __bf16* __restrict__ wf,
    __bf16* __restrict__ XfH,
    unsigned* __restrict__ step_done,
    float* __restrict__ h_state) {

    int bx = blockIdx.x;
    int xcd = bx & 7;
    int loc = bx >> 3;                       // 0..31
    int cg = xcd * 2 + (loc >> 4);           // cg pair per XCD -> weights L2-hot
    int bt = loc & 15;                       // every XCD hosts all 16 tiles

    __shared__ __align__(16) __bf16 Bb[4][16384];   // 128 KB quad B buffer
    __shared__ __align__(16) __bf16 zh[4096];       // [plane2][rl64][hc32]
    __shared__ int info_s[64];

    int tid = threadIdx.x;
    int w = tid >> 6, lane = tid & 63, l31 = lane & 31;
    int s = w >> 2, kg = (w >> 1) & 1, n = w & 1;
    int half8 = (lane >> 5) << 3;

    if (tid < 64) info_s[tid] = rowinfo[bt * 64 + tid];
    __syncthreads();
    int t_end = info_s[0] >> 20;             // max seqlen in tile

    int rowl = s * 32 + l31;
    int inf_r = info_s[rowl];
    const int* tokptr = ((((inf_r >> 15) & 1) ? in2 : in1)) + (inf_r & 511) * TT;

    // cell-update constants: thread -> (rl block of 4, hcB)
    int hcB = tid & 31;
    int hcol = cg * 32 + hcB;
    float bi = bias[hcol], bj = bias[512 + hcol];
    float bfv = bias[1024 + hcol], bo = bias[1536 + hcol];

    float c_reg[4] = {0.f, 0.f, 0.f, 0.f};
    float h_reg[4] = {0.f, 0.f, 0.f, 0.f};

    const __bf16* wb = wf + (size_t)cg * WCG;
    auto stageB = [&](int cc) {              // exactly 4 GLL16 / thread
        const __bf16* src = wb + cc * 16384 + w * 2048 + lane * 8;
        __bf16* dst = &Bb[cc & 3][w * 2048 + lane * 8];
#pragma unroll
        for (int i = 0; i < 4; ++i)
            GLL16(src + i * 512, dst + i * 512);
    };

    bf16x8 aH[3][2], aL[3][2];               // 3-deep A fragment rotation
    const __bf16* eb;                        // per-lane emb base, current step
    const __bf16* hrd;                       // per-lane XfH base, current step

    auto loadA = [&](int cc, int set) {      // exactly 4 vmem loads / thread
        if (cc < 6) {
#pragma unroll
            for (int q = 0; q < 2; ++q) {
                aH[set][q] = *(const bf16x8*)(eb + cc * 64 + q * 16);
                aL[set][q] = *(const bf16x8*)(eb + 384 + cc * 64 + q * 16);
            }
        } else {
            int kgL = (cc - 6) & 1, c3 = (cc - 6) >> 1;
            const __bf16* p = hrd + ((s * 2 + kgL) * 4 + c3) * 4096 + kg * 2048;
#pragma unroll
            for (int q = 0; q < 2; ++q) {
                aH[set][q] = *(const bf16x8*)(p + q * 1024);
                aL[set][q] = *(const bf16x8*)(p + q * 1024 + 512);
            }
        }
    };

    // ---- prologue: tok(0); stage(0,1,2); A(0),A(1) ----
    {
        int tok = tokptr[0];
        eb = embB + (size_t)tok * 768 + kg * 32 + half8;
        hrd = XfH + (size_t)bt * 65536 + lane * 8;
        stageB(0); stageB(1); stageB(2);
        SCHED0();
        loadA(0, 0); loadA(1, 1);
        SCHED0();
    }

    float* zs = (float*)&Bb[0][0];           // overlay [kg2][row64][ZST]

    for (int t = 0; t < t_end; ++t) {
        f32x16 acc[2];
#pragma unroll
        for (int gg = 0; gg < 2; ++gg)
#pragma unroll
            for (int r = 0; r < 16; ++r) acc[gg][r] = 0.0f;

#pragma unroll
        for (int cc = 0; cc < 14; ++cc) {
            // gate: ensure stage(cc) retired; counted so stage(cc+1..cc+2)
            // and A(cc..cc+1) stay IN FLIGHT across the barrier
            if (cc == 0)      asm volatile("s_waitcnt vmcnt(16)" ::: "memory");
            else if (cc == 2) asm volatile("s_waitcnt vmcnt(24)" ::: "memory");
            else              asm volatile("s_waitcnt vmcnt(20)" ::: "memory");
            SBAR();
            SCHED0();
            if (cc == 4 && t > 0) {
                // h(t) published by all 16 blocks? (needed before A(6) issue)
                if (tid == 0) {
                    unsigned target = 16u * (unsigned)t;
                    int guard = 0;
                    while (__hip_atomic_load(step_done + bt, __ATOMIC_RELAXED,
                                             __HIP_MEMORY_SCOPE_AGENT) < target) {
                        __builtin_amdgcn_s_sleep(1);
                        if (++guard > (1 << 20)) break;   // never hang
                    }
                }
                SBAR();
                SCHED0();
            }
            if (cc <= 10) { stageB(cc + 3); SCHED0(); }
            if (cc <= 11) { loadA(cc + 2, (cc + 2) % 3); SCHED0(); }
            // compute chunk cc from A set cc%3 + LDS B slots
#pragma unroll
            for (int q = 0; q < 2; ++q) {
#pragma unroll
                for (int gg = 0; gg < 2; ++gg) {
                    int slot = ((2 * kg + q) * 4 + (2 * n + gg)) * 2;
                    const __bf16* bp = &Bb[cc & 3][slot * 512 + lane * 8];
                    bf16x8 bh = *(const bf16x8*)bp;
                    bf16x8 bl = *(const bf16x8*)(bp + 512);
                    acc[gg] = __builtin_amdgcn_mfma_f32_32x32x16_bf16(aH[cc % 3][q], bh, acc[gg], 0, 0, 0);
                    acc[gg] = __builtin_amdgcn_mfma_f32_32x32x16_bf16(aH[cc % 3][q], bl, acc[gg], 0, 0, 0);
                    acc[gg] = __builtin_amdgcn_mfma_f32_32x32x16_bf16(aL[cc % 3][q], bh, acc[gg], 0, 0, 0);
                }
            }
        }

        // ---- step boundary: all buffers consumed; protect zs overlay ----
        SBAR();
        SCHED0();

        // split-k planes: zs[kg][row][gate*32 + col]
#pragma unroll
        for (int gg = 0; gg < 2; ++gg)
#pragma unroll
            for (int r = 0; r < 16; ++r) {
                int row = (r & 3) + ((r >> 2) << 3) + ((lane >> 5) << 2);
                int zrow = s * 32 + row;
                int col = (2 * n + gg) * 32 + l31;
                zs[(kg * 64 + zrow) * ZST + col] = acc[gg][r];
            }
        asm volatile("s_waitcnt lgkmcnt(0)" ::: "memory");
        SBAR();
        SCHED0();

        // ---- LSTM cell update: 64 rows x 32 h-cols, state in registers ----
#pragma unroll
        for (int i = 0; i < 4; ++i) {
            int rl = i * 16 + (tid >> 5);
            int info = info_s[rl];
            int sl = info >> 20;
            float zi = zs[rl * ZST + hcB]            + zs[(64 + rl) * ZST + hcB]            + bi;
            float zj = zs[rl * ZST + 32 + hcB]       + zs[(64 + rl) * ZST + 32 + hcB]       + bj;
            float zf = zs[rl * ZST + 64 + hcB]       + zs[(64 + rl) * ZST + 64 + hcB]       + bfv;
            float zo = zs[rl * ZST + 96 + hcB]       + zs[(64 + rl) * ZST + 96 + hcB]       + bo;
            float c_old = c_reg[i];
            float h_old = h_reg[i];
            float nc = c_old * sigm(zf + 1.0f) + sigm(zi) * tanh_fast(zj);
            float nh = tanh_fast(nc) * sigm(zo);
            bool valid = t < sl;
            float cs = valid ? nc : c_old;
            float hs = valid ? nh : h_old;
            c_reg[i] = cs;
            h_reg[i] = hs;
            __bf16 hh = (__bf16)hs;
            zh[rl * 32 + hcB] = hh;
            zh[2048 + rl * 32 + hcB] = (__bf16)(hs - (float)hh);
        }
        asm volatile("s_waitcnt lgkmcnt(0)" ::: "memory");
        SBAR();
        SCHED0();

        if (t + 1 < t_end) {
            int tok_n = tokptr[t + 1];               // 1 vmem (oldest)
            SCHED0();
            // publish h-frag for step t+1 (2 sc1 stores; bypass L2)
            {
                int rl = tid & 63;
                int q  = (tid >> 6) & 1;
                int plane = (tid >> 7) & 1;
                int hf = (tid >> 8) & 1;
                ulonglong2 uv = *(const ulonglong2*)(zh + plane * 2048 + rl * 32 + q * 16 + hf * 8);
                int s2 = rl >> 5, rb = rl & 31;
                int kgL = (cg >> 1) & 1, c3 = cg >> 2, jj = (cg & 1) * 2 + q;
                size_t off = ((size_t)(t + 1) * 16 + bt) * 65536
                           + (size_t)((s2 * 2 + kgL) * 4 + c3) * 4096
                           + jj * 1024 + plane * 512 + (hf * 32 + rb) * 8;
                unsigned long long* dst = (unsigned long long*)(XfH + off);
                __hip_atomic_store(dst,     uv.x, __ATOMIC_RELAXED, __HIP_MEMORY_SCOPE_AGENT);
                __hip_atomic_store(dst + 1, uv.y, __ATOMIC_RELAXED, __HIP_MEMORY_SCOPE_AGENT);
            }
            SCHED0();
            // next-step prologue issues (stay in flight across the signal)
            eb = embB + (size_t)tok_n * 768 + kg * 32 + half8;
            hrd = XfH + ((size_t)(t + 1) * 16 + bt) * 65536 + lane * 8;
            stageB(0); stageB(1); stageB(2);
            SCHED0();
            loadA(0, 0); loadA(1, 1);
            SCHED0();
            // outstanding: tok(1)+pub(2)+stage(12)+A(8)=23 -> vmcnt(20)
            // retires tok+publishes (FIFO), keeps stage/A alive
            asm volatile("s_waitcnt vmcnt(20)" ::: "memory");
            SBAR();
            if (tid == 0)
                __hip_atomic_fetch_add(step_done + bt, 1u, __ATOMIC_RELAXED,
                                       __HIP_MEMORY_SCOPE_AGENT);
        }
    }

    // final h writeback (original batch index layout), once per kernel
#pragma unroll
    for (int i = 0; i < 4; ++i) {
        int rl = i * 16 + (tid >> 5);
        int info = info_s[rl];
        int b = info & 511, sc = (info >> 15) & 1;
        h_state[(size_t)((sc << 9) + b) * HDIM + hcol] = h_reg[i];
    }
}

// ---------------------------------------------------------------------------
// Head stage 1: h_combined [512][2112] as bf16 hi/lo planes
// ---------------------------------------------------------------------------
__global__ __launch_bounds__(256) void head1(const float* __restrict__ h_state,
                                             const int* __restrict__ sl1,
                                             const int* __restrict__ sl2,
                                             __bf16* __restrict__ hch,
                                             __bf16* __restrict__ hcl) {
    int b = blockIdx.x;
    int tid = threadIdx.x;
    const float* h1 = h_state + (size_t)b * HDIM;
    const float* h2 = h_state + (size_t)(512 + b) * HDIM;
    size_t ro = (size_t)b * KP1;
    float l1 = (float)sl1[b] / (float)TT;
    float l2 = (float)sl2[b] / (float)TT;
    float part = 0.0f;
#pragma unroll
    for (int i = 0; i < 2; ++i) {
        int k = i * 256 + tid;
        float a = h1[k], c = h2[k];
        float sv = a - c;
        float mv = a * c;
        __bf16 xh;
        xh = (__bf16)a;  hch[ro + k] = xh;         hcl[ro + k] = (__bf16)(a - (float)xh);
        xh = (__bf16)c;  hch[ro + 513 + k] = xh;   hcl[ro + 513 + k] = (__bf16)(c - (float)xh);
        xh = (__bf16)sv; hch[ro + 1026 + k] = xh;  hcl[ro + 1026 + k] = (__bf16)(sv - (float)xh);
        xh = (__bf16)mv; hch[ro + 1540 + k] = xh;  hcl[ro + 1540 + k] = (__bf16)(mv - (float)xh);
        part += sv * sv;
    }
    __shared__ float red[4];
#pragma unroll
    for (int off = 32; off > 0; off >>= 1) part += __shfl_down(part, off, 64);
    if ((tid & 63) == 0) red[tid >> 6] = part;
    __syncthreads();
    if (tid == 0) {
        float d = red[0] + red[1] + red[2] + red[3];
        float ls = l1 - l2;
        d += ls * ls;
        float vals[5] = {l1, l2, ls, d, l1 * l2};
        int pos[5] = {512, 1025, 1538, 1539, 2052};
#pragma unroll
        for (int i = 0; i < 5; ++i) {
            __bf16 xh = (__bf16)vals[i];
            hch[ro + pos[i]] = xh;
            hcl[ro + pos[i]] = (__bf16)(vals[i] - (float)xh);
        }
    }
}

// ---------------------------------------------------------------------------
// Head stage 2 (MFMA): partials over 4 k-slices of 528
// ---------------------------------------------------------------------------
__global__ __launch_bounds__(512, 2) void head2m(
    const __bf16* __restrict__ hch, const __bf16* __restrict__ hcl,
    const __bf16* __restrict__ w1h, const __bf16* __restrict__ w1l,
    float* __restrict__ part) {

    __shared__ __align__(16) __bf16 Bb[2][64 * 512];

    int tid = threadIdx.x;
    int bx = blockIdx.x;
    int mt = bx >> 3;
    int n2 = (bx >> 2) & 1;
    int ks = bx & 3;
    int w = tid >> 6, lane = tid & 63, l31 = lane & 31;
    int half8 = (lane >> 5) << 3;
    int s = w >> 1, nh = w & 1;
    int kbase = ks * 528;

    int k8 = tid & 15;
    int jb = k8 >> 1;
    int rb = (tid >> 4) & 31;
    size_t gboff[8];
    int lo[8];
#pragma unroll
    for (int i = 0; i < 8; ++i) {
        int r = ((i & 3) << 5) + rb;
        int plane = i >> 2;
        int ng = n2 * 128 + r;
        gboff[i] = (size_t)ng * KP1 + k8 * 8;
        int nt = r >> 5;
        int colp = ((r & 31) + (jb << 2)) & 31;
        lo[i] = ((((jb << 2) + nt) << 1) + plane) * 512 + (colp + ((k8 & 1) << 5)) * 8;
    }

    const __bf16* Ah0 = hch + (size_t)(mt * 128 + s * 32 + l31) * KP1 + kbase + half8;
    const __bf16* Al0 = hcl + (size_t)(mt * 128 + s * 32 + l31) * KP1 + kbase + half8;

    bf16x8 rB[8];
    f32x16 acc[2];
#pragma unroll
    for (int nt = 0; nt < 2; ++nt)
#pragma unroll
        for (int r = 0; r < 16; ++r) acc[nt][r] = 0.0f;

#pragma unroll
    for (int i = 0; i < 8; ++i)
        rB[i] = *(const bf16x8*)(((i >= 4) ? w1l : w1h) + gboff[i] + kbase);
#pragma unroll
    for (int i = 0; i < 8; ++i) *(bf16x8*)(&Bb[0][lo[i]]) = rB[i];
    __syncthreads();

    for (int c = 0; c < 5; ++c) {
        int cur = c & 1;
        if (c < 4) {
            int k0 = kbase + (c + 1) * 128;
            bool tail = (c + 1 == 4);
#pragma unroll
            for (int i = 0; i < 8; ++i) {
                if (!tail || k8 < 2)
                    rB[i] = *(const bf16x8*)(((i >= 4) ? w1l : w1h) + gboff[i] + k0);
            }
        }
        int jmax = (c == 4) ? 1 : 8;
        for (int j = 0; j < jmax; ++j) {
            bf16x8 ah = *(const bf16x8*)(Ah0 + c * 128 + j * 16);
            bf16x8 al = *(const bf16x8*)(Al0 + c * 128 + j * 16);
            int cp = ((l31 + (j << 2)) & 31) + ((lane >> 5) << 5);
#pragma unroll
            for (int ntl = 0; ntl < 2; ++ntl) {
                int ntg = nh * 2 + ntl;
                const __bf16* bp = &Bb[cur][(((j << 2) + ntg) << 1) * 512 + cp * 8];
                bf16x8 bh = *(const bf16x8*)bp;
                bf16x8 bl = *(const bf16x8*)(bp + 512);
                acc[ntl] = __builtin_amdgcn_mfma_f32_32x32x16_bf16(ah, bh, acc[ntl], 0, 0, 0);
                acc[ntl] = __builtin_amdgcn_mfma_f32_32x32x16_bf16(ah, bl, acc[ntl], 0, 0, 0);
                acc[ntl] = __builtin_amdgcn_mfma_f32_32x32x16_bf16(al, bh, acc[ntl], 0, 0, 0);
            }
        }
        if (c < 4) {
#pragma unroll
            for (int i = 0; i < 8; ++i) *(bf16x8*)(&Bb[1 - cur][lo[i]]) = rB[i];
        }
        __syncthreads();
    }

#pragma unroll
    for (int ntl = 0; ntl < 2; ++ntl)
#pragma unroll
        for (int r = 0; r < 16; ++r) {
            int row = mt * 128 + s * 32 + (r & 3) + ((r >> 2) << 3) + ((lane >> 5) << 2);
            int col = n2 * 128 + nh * 64 + ntl * 32 + l31;
            part[((size_t)ks * 512 + row) * MDIM + col] = acc[ntl][r];
        }
}

// ---------------------------------------------------------------------------
// Head stage 3: e1 = relu(sum partials + b1); out = e1 @ W2 + b2
// ---------------------------------------------------------------------------
__global__ __launch_bounds__(256) void head3(const float* __restrict__ part,
                                             const float* __restrict__ b1,
                                             const float* __restrict__ W2,
                                             const float* __restrict__ b2,
                                             float* __restrict__ out) {
    int row = blockIdx.x;
    int tid = threadIdx.x;
    float sv = b1[tid];
#pragma unroll
    for (int ks = 0; ks < 4; ++ks)
        sv += part[((size_t)ks * 512 + row) * MDIM + tid];
    float e = fmaxf(sv, 0.0f);
    float p0 = e * W2[tid * 2 + 0];
    float p1 = e * W2[tid * 2 + 1];
#pragma unroll
    for (int off = 32; off > 0; off >>= 1) {
        p0 += __shfl_down(p0, off, 64);
        p1 += __shfl_down(p1, off, 64);
    }
    __shared__ float r0[4], r1[4];
    if ((tid & 63) == 0) { r0[tid >> 6] = p0; r1[tid >> 6] = p1; }
    __syncthreads();
    if (tid == 0) out[row * 2 + 0] = r0[0] + r0[1] + r0[2] + r0[3] + b2[0];
    if (tid == 1) out[row * 2 + 1] = r1[0] + r1[1] + r1[2] + r1[3] + b2[1];
}

// ---------------------------------------------------------------------------
extern "C" void kernel_launch(void* const* d_in, const int* in_sizes, int n_in,
                              void* d_out, int out_size, void* d_ws, size_t ws_size,
                              hipStream_t stream) {
    const int*   in1  = (const int*)d_in[0];
    const int*   in2  = (const int*)d_in[1];
    const int*   sl1  = (const int*)d_in[2];
    const int*   sl2  = (const int*)d_in[3];
    const float* emb  = (const float*)d_in[4];
    const float* kern = (const float*)d_in[5];
    const float* bias = (const float*)d_in[6];
    const float* W1   = (const float*)d_in[7];
    const float* b1   = (const float*)d_in[8];
    const float* W2   = (const float*)d_in[9];
    const float* b2   = (const float*)d_in[10];
    float* out = (float*)d_out;

    char* ws = (char*)d_ws;
    // ws layout (bytes): identical to round 5
    int*      rowinfo   = (int*)ws;
    unsigned* step_done = (unsigned*)(ws + 4096u);
    float*  h_state = (float*)(ws + 2097152u);
    __bf16* wf   = (__bf16*)(ws + 6291456u);
    __bf16* hch  = (__bf16*)(ws + 13631488u);
    __bf16* hcl  = (__bf16*)(ws + 15794176u);
    __bf16* w1h  = (__bf16*)(ws + 17956864u);
    __bf16* w1l  = (__bf16*)(ws + 19038208u);
    float*  part = (float*)(ws + 20119552u);
    __bf16* embB = (__bf16*)(ws + 23068672u);
    __bf16* XfH  = (__bf16*)(ws + 100663296u);

    // zero hch/hcl pad columns
    hipMemsetAsync(ws + 13631488u, 0, 4325376u, stream);
    // zero XfH region 0 (initial h = 0)
    hipMemsetAsync(ws + 100663296u, 0, 2097152u, stream);

    sort_rows<<<dim3(1), dim3(256), 0, stream>>>(sl1, sl2, rowinfo, step_done);
    prep_w<<<dim3(14 * 32), dim3(256), 0, stream>>>(kern, wf);
    prep_w1<<<dim3(33 * 4), dim3(256), 0, stream>>>(W1, w1h, w1l);
    prep_emb<<<dim3(9375), dim3(256), 0, stream>>>(emb, embB);

    lstm_all<<<dim3(256), dim3(512), 0, stream>>>(
        in1, in2, rowinfo, embB, bias, wf, XfH, step_done, h_state);

    head1<<<dim3(512), dim3(256), 0, stream>>>(h_state, sl1, sl2, hch, hcl);
    head2m<<<dim3(32), dim3(512), 0, stream>>>(hch, hcl, w1h, w1l, part);
    head3<<<dim3(512), dim3(256), 0, stream>>>(part, b1, W2, b2, out);
}

// Round 7
// 1192.157 us; speedup vs baseline: 1.2095x; 1.2095x over previous
//
#include <hip/hip_runtime.h>
#include <hip/hip_bf16.h>

// Problem constants
#define BATCH 512
#define TT 60
#define EDIM 300
#define HDIM 512
#define KP1 2112         // padded K for head GEMM (2053 -> 2112)
#define MDIM 256
#define V48 2400000      // 50000 tokens * 48 runs

typedef __bf16 bf16x4 __attribute__((ext_vector_type(4)));
typedef __bf16 bf16x8 __attribute__((ext_vector_type(8)));
typedef float  f32x16 __attribute__((ext_vector_type(16)));

#define GLL16(g, l) __builtin_amdgcn_global_load_lds( \
    (const __attribute__((address_space(1))) void*)(g), \
    (__attribute__((address_space(3))) void*)(l), 16, 0, 0)

#define SBAR()  __builtin_amdgcn_s_barrier()
#define SCHED0() __builtin_amdgcn_sched_barrier(0)

__device__ __forceinline__ float sigm(float x) {
    return 1.0f / (1.0f + __expf(-x));
}
__device__ __forceinline__ float tanh_fast(float x) {
    float e = __expf(-2.0f * fabsf(x));
    float r = (1.0f - e) / (1.0f + e);
    return x >= 0.0f ? r : -r;
}

// ---------------------------------------------------------------------------
// MERGED-PAIR persistent LSTM (traffic-reduction round):
// 256 blocks x 512 thr = 8 tile-pairs x 32 cg, 1 block/CU. Each block hosts
// TWO adjacent sorted tiles (2p, 2p+1) sharing ONE B staging: the weight
// chunk is staged once per CU instead of twice (GLL16 bypasses L1, so the
// previous 2-blocks/CU structure duplicated every B byte at the L2 port).
// Chip L2->CU traffic drops 235 -> 176 MB/step; per-CU 917 -> 687 KB/step.
// All round-5 layouts preserved: Wf [cg:32][c:7][T:32][lane:64][e:8],
// embB hi/lo table, XfH rotating per-step h-frag buffers + sc1 publish,
// per-pair LLC counter (RELAXED; ordering via vmcnt-draining barriers).
// 8 waves = (tg:2 tile) x (s:2 row-half) x (kg:2 k-half). zs/zh in dedicated
// LDS (no Bb overlay). Counted-vmcnt ledger (per thread / chunk):
//   stage = 4 GLL16, A = 8 loads. Top of chunk cc: outstanding =
//   stage(cc)[4] + A(cc)[8] -> vmcnt(8) retires stage(cc), keeps A(cc).
//   Boundary: tok(1)+pub(2)+stage0(4)+A0(8)=15 -> vmcnt(12) retires tok+pub.
// ---------------------------------------------------------------------------

__global__ __launch_bounds__(256) void sort_rows(const int* __restrict__ sl1,
                                                 const int* __restrict__ sl2,
                                                 int* __restrict__ rowinfo,
                                                 unsigned* __restrict__ step_done) {
    __shared__ unsigned cnt[61];
    __shared__ unsigned off[61];
    int tid = threadIdx.x;
    if (tid < 61) cnt[tid] = 0;
    if (tid >= 64 && tid < 80) step_done[tid - 64] = 0;
    __syncthreads();
    for (int i = tid; i < 1024; i += 256) {
        int sl = (i < 512) ? sl1[i] : sl2[i - 512];
        atomicAdd(&cnt[60 - sl], 1u);
    }
    __syncthreads();
    if (tid == 0) {
        unsigned s = 0;
        for (int k = 0; k < 61; ++k) { off[k] = s; s += cnt[k]; }
    }
    __syncthreads();
    for (int i = tid; i < 1024; i += 256) {
        int sc = i >= 512;
        int b = i & 511;
        int sl = sc ? sl2[b] : sl1[b];
        unsigned pos = atomicAdd(&off[60 - sl], 1u);
        rowinfo[pos] = b | (sc << 15) | (sl << 20);
    }
}

// prep_w (round-5 layout): lstm_kernel [812][2048] fp32 -> Wf hi/lo,
// k-remapped: new k<300 -> kern k; 300..383 -> 0; >=384 -> kern k-84
__global__ __launch_bounds__(256) void prep_w(const float* __restrict__ kern,
                                              __bf16* __restrict__ wf) {
    __shared__ float tile[64][65];
    int bk = blockIdx.x % 14;
    int bn = blockIdx.x / 14;
    int k0 = bk * 64, n0 = bn * 64;
    int tid = threadIdx.x;
#pragma unroll
    for (int i = 0; i < 16; ++i) {
        int id = i * 256 + tid;
        int kk = id >> 6, nn = id & 63;
        int kg = k0 + kk;
        int src = (kg < 300) ? kg : (kg >= 384 ? kg - 84 : -1);
        tile[kk][nn] = (src >= 0) ? kern[(size_t)src * 2048 + n0 + nn] : 0.0f;
    }
    __syncthreads();
    int gate = n0 >> 9;
    int nt = gate >> 1;
#pragma unroll
    for (int i = 0; i < 2; ++i) {
        int id = i * 256 + tid;          // 0..511 = nn(64) x k8(8)
        int nn = id >> 3, k8 = id & 7;
        bf16x8 hv, lv;
#pragma unroll
        for (int j = 0; j < 8; ++j) {
            float v = tile[k8 * 8 + j][nn];
            __bf16 h = (__bf16)v;
            hv[j] = h;
            lv[j] = (__bf16)(v - (float)h);
        }
        int cg = (((n0 & 511) >> 4) + (nn >> 4));
        int hc = nn & 15;
        int lzc = ((gate & 1) << 4) + hc;
        int kglob = k0 + k8 * 8;
        int c = kglob >> 7;
        int j = (kglob >> 4) & 7;
        int half = k8 & 1;
        size_t o = (size_t)cg * 114688 + c * 16384 + (j * 4 + nt * 2) * 512
                 + (half * 32 + lzc) * 8;
        *(bf16x8*)(wf + o) = hv;
        *(bf16x8*)(wf + o + 512) = lv;
    }
}

__global__ __launch_bounds__(256) void prep_w1(const float* __restrict__ W1,
                                               __bf16* __restrict__ w1h,
                                               __bf16* __restrict__ w1l) {
    __shared__ float tile[64][65];
    int bk = blockIdx.x % 33;
    int bn = blockIdx.x / 33;
    int k0 = bk * 64, n0 = bn * 64;
    int tid = threadIdx.x;
#pragma unroll
    for (int i = 0; i < 16; ++i) {
        int id = i * 256 + tid;
        int kk = id >> 6, nn = id & 63;
        int kg = k0 + kk;
        tile[kk][nn] = (kg < 2053) ? W1[(size_t)kg * MDIM + n0 + nn] : 0.0f;
    }
    __syncthreads();
#pragma unroll
    for (int i = 0; i < 2; ++i) {
        int id = i * 256 + tid;
        int nn = id >> 3, k8 = (id & 7) * 8;
        bf16x8 hv, lv;
#pragma unroll
        for (int j = 0; j < 8; ++j) {
            float v = tile[k8 + j][nn];
            __bf16 h = (__bf16)v;
            hv[j] = h;
            lv[j] = (__bf16)(v - (float)h);
        }
        size_t o = (size_t)(n0 + nn) * KP1 + k0 + k8;
        *(bf16x8*)(w1h + o) = hv;
        *(bf16x8*)(w1l + o) = lv;
    }
}

// prep_emb: embeddings [50000][300] fp32 -> embB [50000][hi:384 | lo:384] bf16
__global__ __launch_bounds__(256) void prep_emb(const float* __restrict__ emb,
                                                __bf16* __restrict__ embB) {
    int id = blockIdx.x * 256 + threadIdx.x;
    if (id >= V48) return;
    int tok = id / 48;
    int k8 = id - tok * 48;
    int k0 = k8 * 8;
    float vv[8];
    const float* er = emb + (size_t)tok * EDIM + k0;
    if (k0 + 8 <= EDIM) {
        float4 f0 = *(const float4*)er;
        float4 f1 = *(const float4*)(er + 4);
        vv[0] = f0.x; vv[1] = f0.y; vv[2] = f0.z; vv[3] = f0.w;
        vv[4] = f1.x; vv[5] = f1.y; vv[6] = f1.z; vv[7] = f1.w;
    } else if (k0 < EDIM) {          // k0 == 296: 4 real + 4 pad
        float4 f0 = *(const float4*)er;
        vv[0] = f0.x; vv[1] = f0.y; vv[2] = f0.z; vv[3] = f0.w;
        vv[4] = vv[5] = vv[6] = vv[7] = 0.f;
    } else {
#pragma unroll
        for (int j = 0; j < 8; ++j) vv[j] = 0.f;
    }
    bf16x8 hv, lv;
#pragma unroll
    for (int j = 0; j < 8; ++j) {
        __bf16 h = (__bf16)vv[j];
        hv[j] = h;
        lv[j] = (__bf16)(vv[j] - (float)h);
    }
    size_t o = (size_t)tok * 768 + k0;
    *(bf16x8*)(embB + o) = hv;
    *(bf16x8*)(embB + o + 384) = lv;
}

// ---------------------------------------------------------------------------
// Persistent fused LSTM, merged pairs: 256 blocks x 512 thr, 1 block/CU.
// ---------------------------------------------------------------------------
#define ZSTR 68

__global__ __launch_bounds__(512, 1) void lstm_all(
    const int* __restrict__ in1, const int* __restrict__ in2,
    const int* __restrict__ rowinfo,
    const __bf16* __restrict__ embB, const float* __restrict__ bias,
    const __bf16* __restrict__ wf,
    __bf16* __restrict__ XfH,
    unsigned* __restrict__ step_done,
    float* __restrict__ h_state) {

    int bx = blockIdx.x;
    int xcd = bx & 7;
    int loc = bx >> 3;                               // 0..31
    int cg = ((xcd >> 1) << 3) | (loc & 7);          // cg octet per xcd-pair
    int pair = ((loc >> 3) << 1) | (xcd & 1);        // 0..7 (adjacent tiles)

    __shared__ __align__(16) __bf16 Bb[2][16384];    // 64 KB B double-buffer
    __shared__ float zs[2][2][64][ZSTR];             // 69.6 KB split-k planes
    __shared__ __align__(16) __bf16 zh[2][2048];     // 8 KB publish staging
    __shared__ int info_s[2][64];

    int tid = threadIdx.x;
    int w = tid >> 6, lane = tid & 63, l31 = lane & 31;
    int tg = w >> 2, s = (w >> 1) & 1, kg = w & 1;
    int bt = pair * 2 + tg;                          // this wave's tile

    if (tid < 128) info_s[tid >> 6][tid & 63] = rowinfo[(pair * 2 + (tid >> 6)) * 64 + (tid & 63)];
    __syncthreads();
    int t_end = info_s[0][0] >> 20;                  // pair max seqlen

    // this lane's A-row token stream
    int rowl = s * 32 + l31;
    int inf_r = info_s[tg][rowl];
    const int* tokptr = ((((inf_r >> 15) & 1) ? in2 : in1)) + (inf_r & 511) * TT;

    // cell-update constants (per thread: tile tgc, 64 rows x 16 h-cols / 256)
    int tid2 = tid & 255;
    int tgc = tid >> 8;
    int hc16 = tid2 & 15;
    int hcol = (cg << 4) + hc16;
    float bi = bias[hcol], bj = bias[512 + hcol];
    float bfv = bias[1024 + hcol], bo = bias[1536 + hcol];

    float c_reg[4] = {0.f, 0.f, 0.f, 0.f};
    float h_reg[4] = {0.f, 0.f, 0.f, 0.f};

    const __bf16* wb = wf + (size_t)cg * 114688;
    auto stageB = [&](int c, int buf) {              // exactly 4 GLL16 / thread
        const __bf16* src = wb + c * 16384 + tid * 8;
        __bf16* dst = &Bb[buf][tid * 8];
#pragma unroll
        for (int i = 0; i < 4; ++i)
            GLL16(src + i * 4096, dst + i * 4096);
    };

    int ew = kg * 64 + ((lane >> 5) << 3);           // emb k-base per lane
    size_t hw_off = (size_t)((s * 2 + kg) * 4) * 4096 + lane * 8;

    // ---- prologue: tok(0) -> stage(0)->buf0 -> A(0) emb loads ----
    int tok = tokptr[0];                             // 1 vmem (oldest)
    stageB(0, 0);                                    // 4 vmem
    SCHED0();
    bf16x8 aH[4], aL[4];
    const __bf16* eb = embB + (size_t)tok * 768 + ew;
#pragma unroll
    for (int jj = 0; jj < 4; ++jj) {                 // 8 vmem
        aH[jj] = *(const bf16x8*)(eb + jj * 16);
        aL[jj] = *(const bf16x8*)(eb + 384 + jj * 16);
    }
    SCHED0();

    for (int t = 0; t < t_end; ++t) {
        f32x16 acc[2];
#pragma unroll
        for (int nt = 0; nt < 2; ++nt)
#pragma unroll
            for (int r = 0; r < 16; ++r) acc[nt][r] = 0.0f;

        const __bf16* hrd = XfH + ((size_t)t * 16 + bt) * 65536 + hw_off;

#pragma unroll
        for (int c = 0; c < 7; ++c) {
            int cur = (t + c) & 1;
            // stage(c) landed (8 newest outstanding = A(c), kept in flight)
            asm volatile("s_waitcnt vmcnt(8)" ::: "memory");
            SBAR();
            SCHED0();
            if (c == 2 && t > 0) {
                // h(t) published by all 32 blocks of this pair?
                if (tid == 0) {
                    unsigned target = 32u * (unsigned)t;
                    int guard = 0;
                    while (__hip_atomic_load(step_done + pair, __ATOMIC_RELAXED,
                                             __HIP_MEMORY_SCOPE_AGENT) < target) {
                        __builtin_amdgcn_s_sleep(1);
                        if (++guard > (1 << 20)) break;   // never hang
                    }
                }
                SBAR();
                SCHED0();
            }
            bf16x8 nH[4], nL[4];
            if (c < 6) {
                stageB(c + 1, 1 - cur);              // 4 vmem
                SCHED0();
                if (c < 2) {                         // emb chunks 1,2: 8 vmem
                    const __bf16* en = eb + (c + 1) * 128;
#pragma unroll
                    for (int jj = 0; jj < 4; ++jj) {
                        nH[jj] = *(const bf16x8*)(en + jj * 16);
                        nL[jj] = *(const bf16x8*)(en + 384 + jj * 16);
                    }
                } else {                             // h chunks 3..6: 8 vmem
                    const __bf16* An = hrd + (c - 2) * 4096;
#pragma unroll
                    for (int jj = 0; jj < 4; ++jj) {
                        nH[jj] = *(const bf16x8*)(An + jj * 1024);
                        nL[jj] = *(const bf16x8*)(An + jj * 1024 + 512);
                    }
                }
                SCHED0();
            }
#pragma unroll
            for (int jj = 0; jj < 4; ++jj) {
                int j = kg * 4 + jj;
#pragma unroll
                for (int nt = 0; nt < 2; ++nt) {
                    int T0 = (j * 4 + nt * 2) * 512 + lane * 8;
                    bf16x8 bh = *(const bf16x8*)(&Bb[cur][T0]);
                    bf16x8 bl = *(const bf16x8*)(&Bb[cur][T0 + 512]);
                    acc[nt] = __builtin_amdgcn_mfma_f32_32x32x16_bf16(aH[jj], bh, acc[nt], 0, 0, 0);
                    acc[nt] = __builtin_amdgcn_mfma_f32_32x32x16_bf16(aH[jj], bl, acc[nt], 0, 0, 0);
                    acc[nt] = __builtin_amdgcn_mfma_f32_32x32x16_bf16(aL[jj], bh, acc[nt], 0, 0, 0);
                }
            }
            if (c < 6) {
#pragma unroll
                for (int jj = 0; jj < 4; ++jj) { aH[jj] = nH[jj]; aL[jj] = nL[jj]; }
            }
        }

        // ---- step boundary (per-wave zs slots: no pre-barrier needed) ----
        int tn = (t + 1 < TT) ? t + 1 : TT - 1;
        int tok_n = tokptr[tn];                      // 1 vmem, issued early
        SCHED0();

#pragma unroll
        for (int nt = 0; nt < 2; ++nt)
#pragma unroll
            for (int r = 0; r < 16; ++r) {
                int rl = s * 32 + (r & 3) + ((r >> 2) << 3) + ((lane >> 5) << 2);
                zs[tg][kg][rl][nt * 32 + l31] = acc[nt][r];
            }
        asm volatile("s_waitcnt lgkmcnt(0)" ::: "memory");
        SBAR();
        SCHED0();

        // ---- LSTM cell update: 2 tiles x 64 rows x 16 h-cols / 512 thr ----
#pragma unroll
        for (int i = 0; i < 4; ++i) {
            int rl = i * 16 + (tid2 >> 4);
            int info = info_s[tgc][rl];
            int sl = info >> 20;
            float zi = zs[tgc][0][rl][hc16]      + zs[tgc][1][rl][hc16]      + bi;
            float zj = zs[tgc][0][rl][16 + hc16] + zs[tgc][1][rl][16 + hc16] + bj;
            float zf = zs[tgc][0][rl][32 + hc16] + zs[tgc][1][rl][32 + hc16] + bfv;
            float zo = zs[tgc][0][rl][48 + hc16] + zs[tgc][1][rl][48 + hc16] + bo;
            float c_old = c_reg[i];
            float h_old = h_reg[i];
            float nc = c_old * sigm(zf + 1.0f) + sigm(zi) * tanh_fast(zj);
            float nh = tanh_fast(nc) * sigm(zo);
            bool valid = t < sl;
            float cs = valid ? nc : c_old;
            float hs = valid ? nh : h_old;
            c_reg[i] = cs;
            h_reg[i] = hs;
            __bf16 hh = (__bf16)hs;
            int grp = hc16 >> 3, e = hc16 & 7;
            zh[tgc][(grp * 64 + rl) * 8 + e] = hh;
            zh[tgc][((2 + grp) * 64 + rl) * 8 + e] = (__bf16)(hs - (float)hh);
        }
        asm volatile("s_waitcnt lgkmcnt(0)" ::: "memory");
        SBAR();
        SCHED0();

        if (t + 1 < t_end) {
            // publish both tiles' h-frags for step t+1 (2 sc1 stores/thread)
            {
                int plane = (tid2 >> 7) & 1;
                int grp = (tid2 >> 6) & 1;
                int rl = tid2 & 63;
                ulonglong2 uv = *(const ulonglong2*)(&zh[tgc][((plane * 2 + grp) * 64 + rl) * 8]);
                int s2 = rl >> 5;
                int bt_p = pair * 2 + tgc;
                size_t base = ((size_t)(t + 1) * 16 + bt_p) * 65536
                            + (size_t)((s2 * 2 + ((cg >> 2) & 1)) * 4 + (cg >> 3)) * 4096
                            + (cg & 3) * 1024 + plane * 512 + (grp * 32 + (rl & 31)) * 8;
                unsigned long long* dst = (unsigned long long*)(XfH + base);
                __hip_atomic_store(dst,     uv.x, __ATOMIC_RELAXED, __HIP_MEMORY_SCOPE_AGENT);
                __hip_atomic_store(dst + 1, uv.y, __ATOMIC_RELAXED, __HIP_MEMORY_SCOPE_AGENT);
            }
            SCHED0();
            // next-step prefetch: stage(0) then A(0)
            stageB(0, (t + 1) & 1);
            SCHED0();
            eb = embB + (size_t)tok_n * 768 + ew;
#pragma unroll
            for (int jj = 0; jj < 4; ++jj) {
                aH[jj] = *(const bf16x8*)(eb + jj * 16);
                aL[jj] = *(const bf16x8*)(eb + 384 + jj * 16);
            }
            SCHED0();
            // outstanding: tok(1)+pub(2)+stage(4)+A(8)=15 -> vmcnt(12)
            // retires tok+publishes (FIFO), keeps stage/A alive
            asm volatile("s_waitcnt vmcnt(12)" ::: "memory");
            SBAR();
            if (tid == 0)
                __hip_atomic_fetch_add(step_done + pair, 1u, __ATOMIC_RELAXED,
                                       __HIP_MEMORY_SCOPE_AGENT);
        }
    }

    // final h writeback (original batch index layout), once per kernel
#pragma unroll
    for (int i = 0; i < 4; ++i) {
        int rl = i * 16 + (tid2 >> 4);
        int info = info_s[tgc][rl];
        int b = info & 511, sc = (info >> 15) & 1;
        h_state[(size_t)((sc << 9) + b) * HDIM + hcol] = h_reg[i];
    }
}

// ---------------------------------------------------------------------------
// Head stage 1: h_combined [512][2112] as bf16 hi/lo planes
// ---------------------------------------------------------------------------
__global__ __launch_bounds__(256) void head1(const float* __restrict__ h_state,
                                             const int* __restrict__ sl1,
                                             const int* __restrict__ sl2,
                                             __bf16* __restrict__ hch,
                                             __bf16* __restrict__ hcl) {
    int b = blockIdx.x;
    int tid = threadIdx.x;
    const float* h1 = h_state + (size_t)b * HDIM;
    const float* h2 = h_state + (size_t)(512 + b) * HDIM;
    size_t ro = (size_t)b * KP1;
    float l1 = (float)sl1[b] / (float)TT;
    float l2 = (float)sl2[b] / (float)TT;
    float part = 0.0f;
#pragma unroll
    for (int i = 0; i < 2; ++i) {
        int k = i * 256 + tid;
        float a = h1[k], c = h2[k];
        float sv = a - c;
        float mv = a * c;
        __bf16 xh;
        xh = (__bf16)a;  hch[ro + k] = xh;         hcl[ro + k] = (__bf16)(a - (float)xh);
        xh = (__bf16)c;  hch[ro + 513 + k] = xh;   hcl[ro + 513 + k] = (__bf16)(c - (float)xh);
        xh = (__bf16)sv; hch[ro + 1026 + k] = xh;  hcl[ro + 1026 + k] = (__bf16)(sv - (float)xh);
        xh = (__bf16)mv; hch[ro + 1540 + k] = xh;  hcl[ro + 1540 + k] = (__bf16)(mv - (float)xh);
        part += sv * sv;
    }
    __shared__ float red[4];
#pragma unroll
    for (int off = 32; off > 0; off >>= 1) part += __shfl_down(part, off, 64);
    if ((tid & 63) == 0) red[tid >> 6] = part;
    __syncthreads();
    if (tid == 0) {
        float d = red[0] + red[1] + red[2] + red[3];
        float ls = l1 - l2;
        d += ls * ls;
        float vals[5] = {l1, l2, ls, d, l1 * l2};
        int pos[5] = {512, 1025, 1538, 1539, 2052};
#pragma unroll
        for (int i = 0; i < 5; ++i) {
            __bf16 xh = (__bf16)vals[i];
            hch[ro + pos[i]] = xh;
            hcl[ro + pos[i]] = (__bf16)(vals[i] - (float)xh);
        }
    }
}

// ---------------------------------------------------------------------------
// Head stage 2 (MFMA): partials over 4 k-slices of 528
// ---------------------------------------------------------------------------
__global__ __launch_bounds__(512, 2) void head2m(
    const __bf16* __restrict__ hch, const __bf16* __restrict__ hcl,
    const __bf16* __restrict__ w1h, const __bf16* __restrict__ w1l,
    float* __restrict__ part) {

    __shared__ __align__(16) __bf16 Bb[2][64 * 512];

    int tid = threadIdx.x;
    int bx = blockIdx.x;
    int mt = bx >> 3;
    int n2 = (bx >> 2) & 1;
    int ks = bx & 3;
    int w = tid >> 6, lane = tid & 63, l31 = lane & 31;
    int half8 = (lane >> 5) << 3;
    int s = w >> 1, nh = w & 1;
    int kbase = ks * 528;

    int k8 = tid & 15;
    int jb = k8 >> 1;
    int rb = (tid >> 4) & 31;
    size_t gboff[8];
    int lo[8];
#pragma unroll
    for (int i = 0; i < 8; ++i) {
        int r = ((i & 3) << 5) + rb;
        int plane = i >> 2;
        int ng = n2 * 128 + r;
        gboff[i] = (size_t)ng * KP1 + k8 * 8;
        int nt = r >> 5;
        int colp = ((r & 31) + (jb << 2)) & 31;
        lo[i] = ((((jb << 2) + nt) << 1) + plane) * 512 + (colp + ((k8 & 1) << 5)) * 8;
    }

    const __bf16* Ah0 = hch + (size_t)(mt * 128 + s * 32 + l31) * KP1 + kbase + half8;
    const __bf16* Al0 = hcl + (size_t)(mt * 128 + s * 32 + l31) * KP1 + kbase + half8;

    bf16x8 rB[8];
    f32x16 acc[2];
#pragma unroll
    for (int nt = 0; nt < 2; ++nt)
#pragma unroll
        for (int r = 0; r < 16; ++r) acc[nt][r] = 0.0f;

#pragma unroll
    for (int i = 0; i < 8; ++i)
        rB[i] = *(const bf16x8*)(((i >= 4) ? w1l : w1h) + gboff[i] + kbase);
#pragma unroll
    for (int i = 0; i < 8; ++i) *(bf16x8*)(&Bb[0][lo[i]]) = rB[i];
    __syncthreads();

    for (int c = 0; c < 5; ++c) {
        int cur = c & 1;
        if (c < 4) {
            int k0 = kbase + (c + 1) * 128;
            bool tail = (c + 1 == 4);
#pragma unroll
            for (int i = 0; i < 8; ++i) {
                if (!tail || k8 < 2)
                    rB[i] = *(const bf16x8*)(((i >= 4) ? w1l : w1h) + gboff[i] + k0);
            }
        }
        int jmax = (c == 4) ? 1 : 8;
        for (int j = 0; j < jmax; ++j) {
            bf16x8 ah = *(const bf16x8*)(Ah0 + c * 128 + j * 16);
            bf16x8 al = *(const bf16x8*)(Al0 + c * 128 + j * 16);
            int cp = ((l31 + (j << 2)) & 31) + ((lane >> 5) << 5);
#pragma unroll
            for (int ntl = 0; ntl < 2; ++ntl) {
                int ntg = nh * 2 + ntl;
                const __bf16* bp = &Bb[cur][(((j << 2) + ntg) << 1) * 512 + cp * 8];
                bf16x8 bh = *(const bf16x8*)bp;
                bf16x8 bl = *(const bf16x8*)(bp + 512);
                acc[ntl] = __builtin_amdgcn_mfma_f32_32x32x16_bf16(ah, bh, acc[ntl], 0, 0, 0);
                acc[ntl] = __builtin_amdgcn_mfma_f32_32x32x16_bf16(ah, bl, acc[ntl], 0, 0, 0);
                acc[ntl] = __builtin_amdgcn_mfma_f32_32x32x16_bf16(al, bh, acc[ntl], 0, 0, 0);
            }
        }
        if (c < 4) {
#pragma unroll
            for (int i = 0; i < 8; ++i) *(bf16x8*)(&Bb[1 - cur][lo[i]]) = rB[i];
        }
        __syncthreads();
    }

#pragma unroll
    for (int ntl = 0; ntl < 2; ++ntl)
#pragma unroll
        for (int r = 0; r < 16; ++r) {
            int row = mt * 128 + s * 32 + (r & 3) + ((r >> 2) << 3) + ((lane >> 5) << 2);
            int col = n2 * 128 + nh * 64 + ntl * 32 + l31;
            part[((size_t)ks * 512 + row) * MDIM + col] = acc[ntl][r];
        }
}

// ---------------------------------------------------------------------------
// Head stage 3: e1 = relu(sum partials + b1); out = e1 @ W2 + b2
// ---------------------------------------------------------------------------
__global__ __launch_bounds__(256) void head3(const float* __restrict__ part,
                                             const float* __restrict__ b1,
                                             const float* __restrict__ W2,
                                             const float* __restrict__ b2,
                                             float* __restrict__ out) {
    int row = blockIdx.x;
    int tid = threadIdx.x;
    float sv = b1[tid];
#pragma unroll
    for (int ks = 0; ks < 4; ++ks)
        sv += part[((size_t)ks * 512 + row) * MDIM + tid];
    float e = fmaxf(sv, 0.0f);
    float p0 = e * W2[tid * 2 + 0];
    float p1 = e * W2[tid * 2 + 1];
#pragma unroll
    for (int off = 32; off > 0; off >>= 1) {
        p0 += __shfl_down(p0, off, 64);
        p1 += __shfl_down(p1, off, 64);
    }
    __shared__ float r0[4], r1[4];
    if ((tid & 63) == 0) { r0[tid >> 6] = p0; r1[tid >> 6] = p1; }
    __syncthreads();
    if (tid == 0) out[row * 2 + 0] = r0[0] + r0[1] + r0[2] + r0[3] + b2[0];
    if (tid == 1) out[row * 2 + 1] = r1[0] + r1[1] + r1[2] + r1[3] + b2[1];
}

// ---------------------------------------------------------------------------
extern "C" void kernel_launch(void* const* d_in, const int* in_sizes, int n_in,
                              void* d_out, int out_size, void* d_ws, size_t ws_size,
                              hipStream_t stream) {
    const int*   in1  = (const int*)d_in[0];
    const int*   in2  = (const int*)d_in[1];
    const int*   sl1  = (const int*)d_in[2];
    const int*   sl2  = (const int*)d_in[3];
    const float* emb  = (const float*)d_in[4];
    const float* kern = (const float*)d_in[5];
    const float* bias = (const float*)d_in[6];
    const float* W1   = (const float*)d_in[7];
    const float* b1   = (const float*)d_in[8];
    const float* W2   = (const float*)d_in[9];
    const float* b2   = (const float*)d_in[10];
    float* out = (float*)d_out;

    char* ws = (char*)d_ws;
    // ws layout (bytes): identical to round 5
    int*      rowinfo   = (int*)ws;
    unsigned* step_done = (unsigned*)(ws + 4096u);
    float*  h_state = (float*)(ws + 2097152u);
    __bf16* wf   = (__bf16*)(ws + 6291456u);
    __bf16* hch  = (__bf16*)(ws + 13631488u);
    __bf16* hcl  = (__bf16*)(ws + 15794176u);
    __bf16* w1h  = (__bf16*)(ws + 17956864u);
    __bf16* w1l  = (__bf16*)(ws + 19038208u);
    float*  part = (float*)(ws + 20119552u);
    __bf16* embB = (__bf16*)(ws + 23068672u);
    __bf16* XfH  = (__bf16*)(ws + 100663296u);

    // zero hch/hcl pad columns
    hipMemsetAsync(ws + 13631488u, 0, 4325376u, stream);
    // zero XfH region 0 (initial h = 0)
    hipMemsetAsync(ws + 100663296u, 0, 2097152u, stream);

    sort_rows<<<dim3(1), dim3(256), 0, stream>>>(sl1, sl2, rowinfo, step_done);
    prep_w<<<dim3(14 * 32), dim3(256), 0, stream>>>(kern, wf);
    prep_w1<<<dim3(33 * 4), dim3(256), 0, stream>>>(W1, w1h, w1l);
    prep_emb<<<dim3(9375), dim3(256), 0, stream>>>(emb, embB);

    lstm_all<<<dim3(256), dim3(512), 0, stream>>>(
        in1, in2, rowinfo, embB, bias, wf, XfH, step_done, h_state);

    head1<<<dim3(512), dim3(256), 0, stream>>>(h_state, sl1, sl2, hch, hcl);
    head2m<<<dim3(32), dim3(512), 0, stream>>>(hch, hcl, w1h, w1l, part);
    head3<<<dim3(512), dim3(256), 0, stream>>>(part, b1, W2, b2, out);
}